// Round 1
// baseline (436.705 us; speedup 1.0000x reference)
//
#include <hip/hip_runtime.h>

#define N 8192
#define DIN 512
#define DOUT 256
#define ALPHA 0.2f
#define NEG_INF -9.0e15f

typedef __attribute__((ext_vector_type(8))) short bf16x8;
typedef __attribute__((ext_vector_type(4))) float f32x4;
typedef __attribute__((ext_vector_type(4))) int   i32x4;

__device__ __forceinline__ unsigned f2bf_u(float f) {
    unsigned u = __builtin_bit_cast(unsigned, f);
    return (u + 0x7fffu + ((u >> 16) & 1u)) >> 16;   // RNE bf16
}
__device__ __forceinline__ unsigned pack2bf(float lo, float hi) {
    return f2bf_u(lo) | (f2bf_u(hi) << 16);
}
union U4BF8 { uint4 u; bf16x8 v; };

__device__ __forceinline__ void async_copy16(const ushort* g, ushort* l) {
    __builtin_amdgcn_global_load_lds(
        (const __attribute__((address_space(1))) unsigned*)g,
        (__attribute__((address_space(3))) unsigned*)l, 16, 0, 0);
}

// Kernel 0: W fp32 [512][256] -> WB bf16 in MFMA-B layout ((k>>3)*256+c)*8+(k&7).
__global__ __launch_bounds__(256) void wb_kernel(const float* __restrict__ W,
                                                 ushort* __restrict__ WB) {
    const int g = blockIdx.x * 256 + threadIdx.x;   // 64*256 = 16384
    const int c = g & 255, k8 = g >> 8;
    const float* wp = W + (size_t)(k8 * 8) * DOUT + c;
    U4BF8 o;
    o.u.x = pack2bf(wp[0 * DOUT], wp[1 * DOUT]);
    o.u.y = pack2bf(wp[2 * DOUT], wp[3 * DOUT]);
    o.u.z = pack2bf(wp[4 * DOUT], wp[5 * DOUT]);
    o.u.w = pack2bf(wp[6 * DOUT], wp[7 * DOUT]);
    *(uint4*)(WB + (size_t)g * 8) = o.u;
}

// Kernel 1: h = X@W + b via MFMA, split-K across 4 waves (unchanged).
__global__ __launch_bounds__(256) void h_kernel(
        const float* __restrict__ X, const ushort* __restrict__ WB,
        const float* __restrict__ bvec, const float* __restrict__ a,
        ushort* __restrict__ hB, float* __restrict__ el, float* __restrict__ er)
{
    __shared__ float red[4][64][65];
    __shared__ float elr[2][4][16];
    const int t = threadIdx.x;
    const int w = t >> 6, l = t & 63, q = l >> 4, n = l & 15;
    const int i0 = blockIdx.x * 16;
    f32x4 acc[16];
    #pragma unroll
    for (int ct = 0; ct < 16; ++ct) acc[ct] = (f32x4){0.f, 0.f, 0.f, 0.f};
    const float* xp = X + (size_t)(i0 + n) * DIN + q * 8;

    #pragma unroll
    for (int ks = 0; ks < 4; ++ks) {
        const int k0 = w * 128 + ks * 32;
        const float4 x0 = *(const float4*)(xp + k0);
        const float4 x1 = *(const float4*)(xp + k0 + 4);
        U4BF8 pa;
        pa.u.x = pack2bf(x0.x, x0.y); pa.u.y = pack2bf(x0.z, x0.w);
        pa.u.z = pack2bf(x1.x, x1.y); pa.u.w = pack2bf(x1.z, x1.w);
        const ushort* wbp = WB + ((k0 >> 3) + q) * 2048 + n * 8;
        bf16x8 bfr[16];
        #pragma unroll
        for (int ct = 0; ct < 16; ++ct) bfr[ct] = *(const bf16x8*)(wbp + ct * 128);
        #pragma unroll
        for (int ct = 0; ct < 16; ++ct)
            acc[ct] = __builtin_amdgcn_mfma_f32_16x16x32_bf16(pa.v, bfr[ct], acc[ct], 0, 0, 0);
    }
    #pragma unroll
    for (int ct = 0; ct < 16; ++ct)
        #pragma unroll
        for (int r = 0; r < 4; ++r) red[w][l][ct * 4 + r] = acc[ct][r];
    __syncthreads();

    float pl[4] = {0.f, 0.f, 0.f, 0.f}, pr[4] = {0.f, 0.f, 0.f, 0.f};
    const int hbase = (blockIdx.x * 2 + (q >> 1)) * 2048 + n * 8 + (q & 1) * 4;
    #pragma unroll
    for (int c2 = 0; c2 < 4; ++c2) {
        const int ct = w * 4 + c2;
        const float bb = bvec[ct * 16 + n];
        const float al = a[ct * 16 + n];
        const float ar = a[DOUT + ct * 16 + n];
        float v[4];
        #pragma unroll
        for (int r = 0; r < 4; ++r) {
            v[r] = red[0][l][ct * 4 + r] + red[1][l][ct * 4 + r]
                 + red[2][l][ct * 4 + r] + red[3][l][ct * 4 + r] + bb;
            pl[r] += v[r] * al;
            pr[r] += v[r] * ar;
        }
        ushort4 hp;
        hp.x = (ushort)f2bf_u(v[0]); hp.y = (ushort)f2bf_u(v[1]);
        hp.z = (ushort)f2bf_u(v[2]); hp.w = (ushort)f2bf_u(v[3]);
        *(ushort4*)&hB[hbase + ct * 128] = hp;
    }
    #pragma unroll
    for (int r = 0; r < 4; ++r) {
        #pragma unroll
        for (int off = 1; off < 16; off <<= 1) {
            pl[r] += __shfl_xor(pl[r], off);
            pr[r] += __shfl_xor(pr[r], off);
        }
    }
    if (n == 0) {
        #pragma unroll
        for (int r = 0; r < 4; ++r) {
            elr[0][w][q * 4 + r] = pl[r];
            elr[1][w][q * 4 + r] = pr[r];
        }
    }
    __syncthreads();
    if (t < 16) {
        el[i0 + t] = elr[0][0][t] + elr[0][1][t] + elr[0][2][t] + elr[0][3][t];
        er[i0 + t] = elr[1][0][t] + elr[1][1][t] + elr[1][2][t] + elr[1][3][t];
    }
}

// 8 masked-exp lanes -> one packed A-fragment word-group + running sum.
#define EXP8(ELM, E0, E1, M0, M1, PA, LS)                                          \
    {                                                                              \
        float v, p0, p1, p2, p3, p4, p5, p6, p7;                                   \
        v = ELM + E0.x; v = fmaxf(v, ALPHA * v); p0 = __expf(M0.x > 0 ? v : NEG_INF); \
        v = ELM + E0.y; v = fmaxf(v, ALPHA * v); p1 = __expf(M0.y > 0 ? v : NEG_INF); \
        v = ELM + E0.z; v = fmaxf(v, ALPHA * v); p2 = __expf(M0.z > 0 ? v : NEG_INF); \
        v = ELM + E0.w; v = fmaxf(v, ALPHA * v); p3 = __expf(M0.w > 0 ? v : NEG_INF); \
        v = ELM + E1.x; v = fmaxf(v, ALPHA * v); p4 = __expf(M1.x > 0 ? v : NEG_INF); \
        v = ELM + E1.y; v = fmaxf(v, ALPHA * v); p5 = __expf(M1.y > 0 ? v : NEG_INF); \
        v = ELM + E1.z; v = fmaxf(v, ALPHA * v); p6 = __expf(M1.z > 0 ? v : NEG_INF); \
        v = ELM + E1.w; v = fmaxf(v, ALPHA * v); p7 = __expf(M1.w > 0 ? v : NEG_INF); \
        LS += p0 + p1 + p2 + p3 + p4 + p5 + p6 + p7;                               \
        PA.u.x = pack2bf(p0, p1); PA.u.y = pack2bf(p2, p3);                        \
        PA.u.z = pack2bf(p4, p5); PA.u.w = pack2bf(p6, p7);                        \
    }

// Kernel 2 (v2): attention partials. Grid 256 = 64 row-blocks x 4 jq.
// Block = 256 thr (4 waves); wave w owns 32 rows (2 row-groups of 16);
// j-step = 64 (32 steps). Double-buffered 32 KB hB tiles via global_load_lds,
// shared across the 4 waves (each ds_read_b128 feeds 2 MFMAs -> LDS read
// traffic halved vs v1). LDS/block = 72 KB -> 2 independent blocks/CU, so
// one block's barrier vmcnt(0) drain overlaps the other block's compute.
__global__ __launch_bounds__(256, 2) void attn_kernel(
        const int* __restrict__ adj, const float* __restrict__ el,
        const float* __restrict__ er, const float* __restrict__ ab,
        const ushort* __restrict__ hB, float* __restrict__ pout,
        float* __restrict__ plsum)
{
    __shared__ ushort stage[2][16384];   // 2 x 32 KB (64 j x 256 cols bf16)
    __shared__ float ers[2048];          // 8 KB
    const int t = threadIdx.x;
    const int w = t >> 6, l = t & 63, q = l >> 4, n = l & 15;
    const int rb = blockIdx.x >> 2, jq = blockIdx.x & 3;
    const int j0 = jq * 2048;
    const int row0 = rb * 128 + w * 32 + n;      // row-group 0; rg1 = +16
    const float elm0 = el[row0] + ab[0];
    const float elm1 = el[row0 + 16] + ab[0];
    const int* alp0 = adj + (size_t)row0 * N + j0 + q * 8;
    const int* alp1 = alp0 + (size_t)16 * N;

    f32x4 acc0[16], acc1[16];
    #pragma unroll
    for (int ct = 0; ct < 16; ++ct) {
        acc0[ct] = (f32x4){0.f, 0.f, 0.f, 0.f};
        acc1[ct] = (f32x4){0.f, 0.f, 0.f, 0.f};
    }
    float lsum0 = 0.f, lsum1 = 0.f;

    // prologue: er quarter -> LDS; adj regs for step 0; hB step-0 tile -> stage[0]
    *(float4*)&ers[t * 8]     = *(const float4*)&er[j0 + t * 8];
    *(float4*)&ers[t * 8 + 4] = *(const float4*)&er[j0 + t * 8 + 4];
    i32x4 a0[4], a1[4];
    #pragma unroll
    for (int kg = 0; kg < 2; ++kg) {
        a0[2 * kg]     = __builtin_nontemporal_load((const i32x4*)(alp0 + kg * 32));
        a0[2 * kg + 1] = __builtin_nontemporal_load((const i32x4*)(alp0 + kg * 32 + 4));
        a1[2 * kg]     = __builtin_nontemporal_load((const i32x4*)(alp1 + kg * 32));
        a1[2 * kg + 1] = __builtin_nontemporal_load((const i32x4*)(alp1 + kg * 32 + 4));
    }
    {
        const ushort* g = hB + (size_t)j0 * 256 + t * 8;
        ushort* lb = &stage[0][t * 8];
        #pragma unroll
        for (int i = 0; i < 8; ++i) async_copy16(g + i * 2048, lb + i * 2048);
    }

    for (int s = 0; s < 32; ++s) {
        __syncthreads();                 // stage[s&1] + ers ready; adj regs for s held
        if (s < 31) {                    // issue next hB tile first (stays in flight)
            const ushort* g = hB + (size_t)(j0 + (s + 1) * 64) * 256 + t * 8;
            ushort* lb = &stage[(s + 1) & 1][t * 8];
            #pragma unroll
            for (int i = 0; i < 8; ++i) async_copy16(g + i * 2048, lb + i * 2048);
        }
        // A-fragments: 2 K-groups x 2 row-groups x 8 j per lane
        U4BF8 pa0[2], pa1[2];
        #pragma unroll
        for (int kg = 0; kg < 2; ++kg) {
            const float4 e0 = *(const float4*)&ers[s * 64 + kg * 32 + q * 8];
            const float4 e1 = *(const float4*)&ers[s * 64 + kg * 32 + q * 8 + 4];
            const i32x4 m00 = a0[2 * kg], m01 = a0[2 * kg + 1];
            const i32x4 m10 = a1[2 * kg], m11 = a1[2 * kg + 1];
            EXP8(elm0, e0, e1, m00, m01, pa0[kg], lsum0);
            EXP8(elm1, e0, e1, m10, m11, pa1[kg], lsum1);
        }
        if (s < 31) {                    // adj regs for step s+1
            const int* ap0 = alp0 + (s + 1) * 64;
            const int* ap1 = alp1 + (s + 1) * 64;
            #pragma unroll
            for (int kg = 0; kg < 2; ++kg) {
                a0[2 * kg]     = __builtin_nontemporal_load((const i32x4*)(ap0 + kg * 32));
                a0[2 * kg + 1] = __builtin_nontemporal_load((const i32x4*)(ap0 + kg * 32 + 4));
                a1[2 * kg]     = __builtin_nontemporal_load((const i32x4*)(ap1 + kg * 32));
                a1[2 * kg + 1] = __builtin_nontemporal_load((const i32x4*)(ap1 + kg * 32 + 4));
            }
        }
        #pragma unroll
        for (int kg = 0; kg < 2; ++kg) {
            const ushort* sb = &stage[s & 1][(kg * 4 + q) * 2048 + n * 8];
            #pragma unroll
            for (int ct = 0; ct < 16; ++ct) {
                const bf16x8 bf = *(const bf16x8*)(sb + ct * 128);
                acc0[ct] = __builtin_amdgcn_mfma_f32_16x16x32_bf16(pa0[kg].v, bf, acc0[ct], 0, 0, 0);
                acc1[ct] = __builtin_amdgcn_mfma_f32_16x16x32_bf16(pa1[kg].v, bf, acc1[ct], 0, 0, 0);
            }
        }
    }

    // row sums: reduce across the 4 q-groups holding row n
    lsum0 += __shfl_xor(lsum0, 16); lsum0 += __shfl_xor(lsum0, 32);
    lsum1 += __shfl_xor(lsum1, 16); lsum1 += __shfl_xor(lsum1, 32);
    if (l < 16) {
        plsum[(size_t)jq * N + rb * 128 + w * 32 + l]      = lsum0;
        plsum[(size_t)jq * N + rb * 128 + w * 32 + 16 + l] = lsum1;
    }

    // unnormalized partial tile: rows rb*128 + w*32 + rg*16 + q*4+r, col ct*16+n
    float* pb = pout + ((size_t)jq * N + rb * 128 + w * 32 + q * 4) * 256 + n;
    #pragma unroll
    for (int ct = 0; ct < 16; ++ct)
        #pragma unroll
        for (int r = 0; r < 4; ++r) {
            __builtin_nontemporal_store(acc0[ct][r], pb + (size_t)r * 256 + ct * 16);
            __builtin_nontemporal_store(acc1[ct][r], pb + (size_t)(16 + r) * 256 + ct * 16);
        }
}

// Kernel 3: combine j-quarter partials + normalize. grid 2048 x 256.
__global__ __launch_bounds__(256) void combine_kernel(
        const float* __restrict__ pout, const float* __restrict__ plsum,
        float* __restrict__ out)
{
    const int t = threadIdx.x;
    const int row = blockIdx.x * 4 + (t >> 6);
    const int c = (t & 63) * 4;
    const size_t idx = (size_t)row * 256 + c;
    const size_t qs = (size_t)N * 256;
    float4 v0 = *(const float4*)&pout[idx];
    float4 v1 = *(const float4*)&pout[idx + qs];
    float4 v2 = *(const float4*)&pout[idx + 2 * qs];
    float4 v3 = *(const float4*)&pout[idx + 3 * qs];
    const float li = 1.0f / (plsum[row] + plsum[N + row]
                           + plsum[2 * N + row] + plsum[3 * N + row]);
    float4 o;
    o.x = (v0.x + v1.x + v2.x + v3.x) * li;
    o.y = (v0.y + v1.y + v2.y + v3.y) * li;
    o.z = (v0.z + v1.z + v2.z + v3.z) * li;
    o.w = (v0.w + v1.w + v2.w + v3.w) * li;
    *(float4*)&out[idx] = o;
}

extern "C" void kernel_launch(void* const* d_in, const int* in_sizes, int n_in,
                              void* d_out, int out_size, void* d_ws, size_t ws_size,
                              hipStream_t stream) {
    const int*   adj = (const int*)  d_in[0];
    const float* X   = (const float*)d_in[1];
    const float* W   = (const float*)d_in[2];
    const float* b   = (const float*)d_in[3];
    const float* a   = (const float*)d_in[4];
    const float* ab  = (const float*)d_in[5];
    float* out = (float*)d_out;

    ushort* hB    = (ushort*)d_ws;                        // 4 MB
    ushort* WB    = hB + (size_t)N * DOUT;                // 256 KB
    float*  el    = (float*)(WB + (size_t)DIN * DOUT);    // 32 KB
    float*  er    = el + N;                               // 32 KB
    float*  plsum = er + N;                               // 4*N fp32 = 128 KB
    float*  pout  = plsum + 4 * N;                        // 4*N*256 fp32 = 32 MB

    wb_kernel<<<dim3(64), dim3(256), 0, stream>>>(W, WB);
    h_kernel<<<dim3(N / 16), dim3(256), 0, stream>>>(X, WB, b, a, hB, el, er);
    attn_kernel<<<dim3(256), dim3(256), 0, stream>>>(adj, el, er, ab, hB, pout, plsum);
    combine_kernel<<<dim3(N / 4), dim3(256), 0, stream>>>(pout, plsum, out);
}